// Round 19
// baseline (409.213 us; speedup 1.0000x reference)
//
#include <hip/hip_runtime.h>
#include <math.h>

typedef float f32x4 __attribute__((ext_vector_type(4)));
typedef short short8 __attribute__((ext_vector_type(8)));
typedef unsigned short u16;

#define BB 32
#define CC 192
#define HEADS 6
#define NN 64
#define HID 768
#define NTOK (BB * 64 * 64)
#define SCALE 0.17677669529663687f

#define MFMA(a, b, c) __builtin_amdgcn_mfma_f32_16x16x32_bf16(a, b, c, 0, 0, 0)
// direct global->LDS 16B async copy: per-lane global src, wave-uniform LDS base
#define GLL16(g, l)                                                            \
  __builtin_amdgcn_global_load_lds(                                            \
      (const __attribute__((address_space(1))) void*)(g),                      \
      (__attribute__((address_space(3))) void*)(l), 16, 0, 0)

__device__ __forceinline__ u16 f2bf(float f) {
  union { float f; unsigned int u; } cv;
  cv.f = f;
  unsigned int u = cv.u;
  u += 0x7fffu + ((u >> 16) & 1u);
  return (u16)(u >> 16);
}

__device__ __forceinline__ f32x4 vzero() {
  f32x4 v;
  v[0] = 0.f; v[1] = 0.f; v[2] = 0.f; v[3] = 0.f;
  return v;
}

// exact GELU via Abramowitz-Stegun 7.1.26 erf (|eps|<=1.5e-7)
__device__ __forceinline__ float gelu_f(float x) {
  const float z = 0.70710678118654752f * x;
  const float az = fabsf(z);
  const float tt = __builtin_amdgcn_rcpf(1.0f + 0.3275911f * az);
  const float e = __expf(-az * az);
  float poly = 1.061405429f;
  poly = poly * tt - 1.453152027f;
  poly = poly * tt + 1.421413741f;
  poly = poly * tt - 0.284496736f;
  poly = poly * tt + 0.254829592f;
  float er = 1.0f - poly * tt * e;  // erf(az)
  er = z < 0.f ? -er : er;
  return 0.5f * x * (1.0f + er);
}

// A-style fragment read from swizzled LDS bf16 matrix. pitch in elements.
__device__ __forceinline__ short8 ldsA(const u16* M, int pitch, int r0, int k0, int lane) {
  const int r = r0 + (lane & 15);
  const int cb = ((k0 + ((lane >> 4) << 3)) << 1) ^ ((r & 7) << 4);
  return *(const short8*)(M + r * pitch + (cb >> 1));
}

// B fragment from staged LDS slice [kc][n][8] (n-width = pitch chunks of 192)
__device__ __forceinline__ short8 ldsB(const u16* Wb, int col16, int lane) {
  return *(const short8*)(Wb + (((lane >> 4) * 192) + (col16 << 4) + (lane & 15)) * 8);
}

// ---------------------------------------------------------------------------
// K0: convert weights to bf16 tables in STAGING-CHUNK order.
// ---------------------------------------------------------------------------
__global__ __launch_bounds__(256) void prep_kernel(
    const float* __restrict__ qkvw, const float* __restrict__ pw,
    const float* __restrict__ w1, const float* __restrict__ w2,
    u16* __restrict__ wqkvT, u16* __restrict__ projT,
    u16* __restrict__ w1T, u16* __restrict__ w2T) {
  const int id = blockIdx.x * 256 + threadIdx.x;
  if (id < 576 * 192) {  // wqkvT: [kk 0..5][kc 0..3][n 0..575][8]
    const int e = id & 7;
    const int c = id >> 3;
    const int n = c % 576;
    const int q = c / 576;             // 0..23
    const int kk = q >> 2, kc = q & 3;
    const int k = kk * 32 + kc * 8 + e;
    wqkvT[id] = f2bf(qkvw[k * 576 + n]);
  }
  if (id < 192 * 192) {  // projT: [kk 0..5][kc 0..3][n 0..191][8]
    const int e = id & 7;
    const int c = id >> 3;
    const int n = c % 192;
    const int q = c / 192;             // 0..23
    const int kk = q >> 2, kc = q & 3;
    const int k = kk * 32 + kc * 8 + e;
    projT[id] = f2bf(pw[k * 192 + n]);
  }
  if (id < 768 * 192) {  // w1T: [ph 0..3][kk 0..5][kc 0..3][n 0..191][8]
    const int e = id & 7;
    const int c = id >> 3;
    const int n = c % 192;
    const int q = c / 192;             // 0..95
    const int ph = q / 24, r = q % 24;
    const int kk = r >> 2, kc = r & 3;
    const int k = kk * 32 + kc * 8 + e;        // input channel
    w1T[id] = f2bf(w1[k * 768 + ph * 192 + n]);
  }
  if (id < 192 * 768) {  // w2T: [ph 0..3][kk 0..5][kc 0..3][n 0..191][8]
    const int e = id & 7;
    const int c = id >> 3;
    const int n = c % 192;
    const int q = c / 192;
    const int ph = q / 24, r = q % 24;
    const int kk = r >> 2, kc = r & 3;
    const int k = ph * 192 + kk * 32 + kc * 8 + e;  // hidden channel
    w2T[id] = f2bf(w2[k * 192 + n]);
  }
}

// stage a 768-chunk (12 KB) slice via global_load_lds; 512-thread block
__device__ __forceinline__ void stage768_w8(const u16* tbl, int slice,
                                            u16* dst, int w, int lane) {
  const u16* base = tbl + ((size_t)slice * 768) * 8;
  GLL16(base + (w * 64 + lane) * 8, dst + (w * 64) * 8);
  if (w < 4) GLL16(base + (512 + w * 64 + lane) * 8, dst + (512 + w * 64) * 8);
}

// ---------------------------------------------------------------------------
// K2: fused LN1 + shift + windowed attention. (r16 verbatim + XCD swizzle)
// ---------------------------------------------------------------------------
__global__ __launch_bounds__(512) void attn_kernel(
    const float* __restrict__ x, const float* __restrict__ n1g,
    const float* __restrict__ n1b, const u16* __restrict__ wqkvT,
    const float* __restrict__ qkvb, const float* __restrict__ rpb,
    u16* __restrict__ hw) {
  __shared__ u16 Xs[64 * 192];
  __shared__ u16 Qs[64 * 192];
  __shared__ u16 Ks[64 * 192];
  __shared__ u16 Vt[192 * 64];     // [channel][token]
  __shared__ u16 Pb[2][64 * 64];
  __shared__ u16 Wq[4 * 576 * 8];  // 36 KB, [kc][n][8] for current K-step

  // XCD-aware bijective swizzle (2048 % 8 == 0): contiguous window range/XCD
  const int g = ((blockIdx.x & 7) << 8) | (blockIdx.x >> 3);
  const int t = threadIdx.x;
  const int w = t >> 6;
  const int lane = t & 63;
  const int b = g >> 6;
  const int wr = (g >> 3) & 7, wc = g & 7;
  u16* win = hw + (size_t)g * (64 * 192);

  // ---- LN1 + cyclic shift gather -> Xs (swizzled). 8 lanes per token. ----
  {
    const int n = t >> 3;
    const int ch0 = (t & 7) * 24;
    const int sr = ((wr << 3) + (n >> 3) + 4) & 63;
    const int sc = ((wc << 3) + (n & 7) + 4) & 63;
    const float* xp = x + ((size_t)b * 4096 + sr * 64 + sc) * 192 + ch0;
    float v[24];
    float s = 0.f, sq = 0.f;
#pragma unroll
    for (int q = 0; q < 6; ++q) {
      const float4 f4 = *(const float4*)(xp + q * 4);
      v[q * 4 + 0] = f4.x; v[q * 4 + 1] = f4.y;
      v[q * 4 + 2] = f4.z; v[q * 4 + 3] = f4.w;
    }
#pragma unroll
    for (int q = 0; q < 24; ++q) { s += v[q]; sq += v[q] * v[q]; }
#pragma unroll
    for (int msk = 1; msk < 8; msk <<= 1) {
      s += __shfl_xor(s, msk);
      sq += __shfl_xor(sq, msk);
    }
    const float mean = s * (1.f / 192.f);
    const float var = sq * (1.f / 192.f) - mean * mean;
    const float rstd = rsqrtf(var + 1e-5f);
#pragma unroll
    for (int q = 0; q < 12; ++q) {
      const int ch = ch0 + q * 2;
      const float a0 = (v[q * 2] - mean) * rstd * n1g[ch] + n1b[ch];
      const float a1 = (v[q * 2 + 1] - mean) * rstd * n1g[ch + 1] + n1b[ch + 1];
      const unsigned int pk = (unsigned int)f2bf(a0) | ((unsigned int)f2bf(a1) << 16);
      const int cb = (ch << 1) ^ ((n & 7) << 4);
      *(unsigned int*)&Xs[n * 192 + (cb >> 1)] = pk;
    }
  }

  // ---- QKV GEMM: 64x192 @ 192x576, weights gll-staged per K-step ----
  const int ntbeg = (w < 4) ? w * 5 : 20 + (w - 4) * 4;
  const int ntcnt = (w < 4) ? 5 : 4;
  f32x4 acc[5][4];
#pragma unroll
  for (int p = 0; p < 5; ++p)
#pragma unroll
    for (int m = 0; m < 4; ++m) acc[p][m] = vzero();

  for (int kk = 0; kk < 6; ++kk) {
    {  // stage 2304 chunks = 36 gll issues
      const u16* src = wqkvT + ((size_t)kk * 2304) * 8;
#pragma unroll
      for (int j = 0; j < 4; ++j) {
        const int cb0 = (j * 8 + w) * 64;
        GLL16(src + (cb0 + lane) * 8, Wq + cb0 * 8);
      }
      if (w < 4) {
        const int cb0 = (32 + w) * 64;
        GLL16(src + (cb0 + lane) * 8, Wq + cb0 * 8);
      }
    }
    __syncthreads();  // drain gll (and Xs on first iter)
    short8 a[4];
#pragma unroll
    for (int m = 0; m < 4; ++m) a[m] = ldsA(Xs, 192, m << 4, kk << 5, lane);
#pragma unroll
    for (int p = 0; p < 5; ++p) {
      int nt = ntbeg + p;
      if (nt > 35) nt = 35;  // waves 4-7 duplicate last tile (discarded)
      const short8 bfr = *(const short8*)(
          Wq + (((lane >> 4) * 576) + (nt << 4) + (lane & 15)) * 8);
#pragma unroll
      for (int m = 0; m < 4; ++m) acc[p][m] = MFMA(a[m], bfr, acc[p][m]);
    }
    __syncthreads();  // all reads done before next stage overwrites Wq
  }

#pragma unroll
  for (int p = 0; p < 5; ++p) {
    if (p < ntcnt) {
      const int cg = ((ntbeg + p) << 4) + (lane & 15);
      const float bias = qkvb[cg];
#pragma unroll
      for (int m = 0; m < 4; ++m) {
#pragma unroll
        for (int i = 0; i < 4; ++i) {
          const int r = (m << 4) + ((lane >> 4) << 2) + i;
          const float val = acc[p][m][i] + bias;
          if (cg < 192) {
            const int cb = (cg << 1) ^ ((r & 7) << 4);
            Qs[r * 192 + (cb >> 1)] = f2bf(val * SCALE);
          } else if (cg < 384) {
            const int cb = ((cg - 192) << 1) ^ ((r & 7) << 4);
            Ks[r * 192 + (cb >> 1)] = f2bf(val);
          } else {
            const int vc = cg - 384;
            const int cb = (r << 1) ^ ((vc & 7) << 4);
            Vt[vc * 64 + (cb >> 1)] = f2bf(val);
          }
        }
      }
    }
  }
  __syncthreads();

  // ---- per-head: scores -> in-reg softmax -> PV. wave = (s, mt). ----
  const int s = w >> 2;
  const int mt = w & 3;
  u16* P = Pb[s];
  const int cbase = lane & 15;
  for (int hh = 0; hh < 3; ++hh) {
    const int h = s * 3 + hh;
    const short8 aq = ldsA(Qs, 192, mt << 4, h << 5, lane);
    f32x4 d[4];
#pragma unroll
    for (int kb = 0; kb < 4; ++kb) {
      const short8 bk = ldsA(Ks, 192, kb << 4, h << 5, lane);
      d[kb] = MFMA(aq, bk, vzero());
      const int c = (kb << 4) + cbase;
      const int i2 = c >> 3, j2 = c & 7;
      const int gr2 = (wr << 3) + i2, gc2 = (wc << 3) + j2;
      const int lab2 = (gr2 < 56 ? 0 : (gr2 < 60 ? 1 : 2)) * 3 +
                       (gc2 < 56 ? 0 : (gc2 < 60 ? 1 : 2));
#pragma unroll
      for (int i = 0; i < 4; ++i) {
        const int r = (mt << 4) + ((lane >> 4) << 2) + i;
        const int i1 = r >> 3, j1 = r & 7;
        const int gr1 = (wr << 3) + i1, gc1 = (wc << 3) + j1;
        const int lab1 = (gr1 < 56 ? 0 : (gr1 < 60 ? 1 : 2)) * 3 +
                         (gc1 < 56 ? 0 : (gc1 < 60 ? 1 : 2));
        float v = d[kb][i] + rpb[((i1 - i2 + 7) * 15 + (j1 - j2 + 7)) * HEADS + h];
        if (lab1 != lab2) v -= 100.f;
        d[kb][i] = v;
      }
    }
    // in-register softmax: row r spread over the 16-lane group (lane&15)
    float mx[4], sum[4];
#pragma unroll
    for (int i = 0; i < 4; ++i) {
      mx[i] = fmaxf(fmaxf(d[0][i], d[1][i]), fmaxf(d[2][i], d[3][i]));
    }
#pragma unroll
    for (int msk = 1; msk < 16; msk <<= 1) {
#pragma unroll
      for (int i = 0; i < 4; ++i) mx[i] = fmaxf(mx[i], __shfl_xor(mx[i], msk));
    }
#pragma unroll
    for (int i = 0; i < 4; ++i) sum[i] = 0.f;
#pragma unroll
    for (int kb = 0; kb < 4; ++kb) {
#pragma unroll
      for (int i = 0; i < 4; ++i) {
        const float e = __expf(d[kb][i] - mx[i]);
        d[kb][i] = e;
        sum[i] += e;
      }
    }
#pragma unroll
    for (int msk = 1; msk < 16; msk <<= 1) {
#pragma unroll
      for (int i = 0; i < 4; ++i) sum[i] += __shfl_xor(sum[i], msk);
    }
#pragma unroll
    for (int kb = 0; kb < 4; ++kb) {
      const int c = (kb << 4) + cbase;
#pragma unroll
      for (int i = 0; i < 4; ++i) {
        const int r = (mt << 4) + ((lane >> 4) << 2) + i;
        const int cb = (c << 1) ^ ((r & 7) << 4);
        P[r * 64 + (cb >> 1)] = f2bf(d[kb][i] / sum[i]);
      }
    }
    // PV: O rows 16mt..+15, cols h*32 + nb*16 (reads only this wave's P rows)
#pragma unroll
    for (int nb = 0; nb < 2; ++nb) {
      f32x4 o = vzero();
#pragma unroll
      for (int ks = 0; ks < 2; ++ks) {
        const short8 ap = ldsA(P, 64, mt << 4, ks << 5, lane);
        const short8 bv = ldsA(Vt, 64, (h << 5) + (nb << 4), ks << 5, lane);
        o = MFMA(ap, bv, o);
      }
      const int c = (h << 5) + (nb << 4) + (lane & 15);
#pragma unroll
      for (int i = 0; i < 4; ++i) {
        const int r = (mt << 4) + ((lane >> 4) << 2) + i;
        win[r * 192 + c] = f2bf(o[i]);
      }
    }
  }
}

// ---------------------------------------------------------------------------
// K3: proj GEMM (gll-staged dbuf) + bias + reverse shift scatter + residual.
// (r16 verbatim + XCD swizzle)
// ---------------------------------------------------------------------------
__global__ __launch_bounds__(256) void proj_kernel(
    const u16* __restrict__ hw, const u16* __restrict__ projT,
    const float* __restrict__ pb, const float* __restrict__ x,
    float* __restrict__ out) {
  __shared__ __align__(16) char sbuf[49152];
  u16* Os = (u16*)sbuf;                 // 24 KB input tile
  u16* Wp0 = (u16*)(sbuf + 24576);      // 12 KB weight slice buf 0
  u16* Wp1 = (u16*)(sbuf + 36864);      // 12 KB weight slice buf 1
  float* Ef = (float*)sbuf;             // 48 KB fp32 epilogue (aliases all)
  const int g = ((blockIdx.x & 7) << 8) | (blockIdx.x >> 3);
  const int t = threadIdx.x;
  const int w = t >> 6;
  const int lane = t & 63;
  const int b_ = g >> 6;
  const int wr = (g >> 3) & 7, wc = g & 7;
  const u16* win = hw + (size_t)g * (64 * 192);
#pragma unroll
  for (int u = 0; u < 6; ++u) {
    const int d = (t * 6 + u) << 4;
    const int row = d / 384;
    const int cb = d - row * 384;
    const short8 v = *(const short8*)((const char*)win + d);
    *(short8*)((char*)Os + row * 384 + (cb ^ ((row & 7) << 4))) = v;
  }
  // prologue stage kk=0 (3 gll issues per wave)
#pragma unroll
  for (int j = 0; j < 3; ++j) {
    const int cb0 = (j * 4 + w) * 64;
    GLL16(projT + (cb0 + lane) * 8, Wp0 + cb0 * 8);
  }
  int cur = 0;
  f32x4 acc[12];
#pragma unroll
  for (int q = 0; q < 12; ++q) acc[q] = vzero();
  for (int kk = 0; kk < 6; ++kk) {
    __syncthreads();  // Os + Wp[cur] ready
    if (kk < 5) {
      const u16* src = projT + ((size_t)(kk + 1) * 768) * 8;
      u16* dstW = cur ? Wp0 : Wp1;
#pragma unroll
      for (int j = 0; j < 3; ++j) {
        const int cb0 = (j * 4 + w) * 64;
        GLL16(src + (cb0 + lane) * 8, dstW + cb0 * 8);
      }
    }
    const short8 a = ldsA(Os, 192, w << 4, kk << 5, lane);
    const u16* curW = cur ? Wp1 : Wp0;
#pragma unroll
    for (int q = 0; q < 12; ++q) acc[q] = MFMA(a, ldsB(curW, q, lane), acc[q]);
    cur ^= 1;
  }
  __syncthreads();  // all Os/Wp reads done before Ef alias writes
  // collect fp32 acc (no bias) into Ef, float4-granule XOR swizzle
#pragma unroll
  for (int q = 0; q < 12; ++q) {
    const int col = (q << 4) + (lane & 15);
#pragma unroll
    for (int i = 0; i < 4; ++i) {
      const int r = (w << 4) + ((lane >> 4) << 2) + i;
      Ef[r * 192 + (col ^ ((r & 7) << 2))] = acc[q][i];
    }
  }
  __syncthreads();
  // cooperative coalesced RMW: 4 threads per token, 48 floats each
  {
    const int tok = t >> 2;
    const int c0 = (t & 3) * 48;
    const int dr = ((wr << 3) + (tok >> 3) + 4) & 63;
    const int dc = ((wc << 3) + (tok & 7) + 4) & 63;
    const size_t dst = ((size_t)b_ * 4096 + dr * 64 + dc) * 192 + c0;
    const float* erow = Ef + tok * 192;
    const int swz = (tok & 7) << 2;
#pragma unroll
    for (int j = 0; j < 12; ++j) {
      const float4 ov = *(const float4*)(erow + ((c0 + j * 4) ^ swz));
      const float4 bv = *(const float4*)(pb + c0 + j * 4);
      float4 xv = *(const float4*)(x + dst + j * 4);
      xv.x = (xv.x + ov.x) + bv.x;
      xv.y = (xv.y + ov.y) + bv.y;
      xv.z = (xv.z + ov.z) + bv.z;
      xv.w = (xv.w + ov.w) + bv.w;
      *(float4*)(out + dst + j * 4) = xv;
    }
  }
}

// ---------------------------------------------------------------------------
// K4: LN2 + fc1 + GELU(A&S) + fc2 + residual. (r16 verbatim)
// ---------------------------------------------------------------------------
__global__ __launch_bounds__(512, 4) void mlp_kernel(
    float* __restrict__ out, const float* __restrict__ g2,
    const float* __restrict__ bn2, const u16* __restrict__ w1T,
    const float* __restrict__ b1, const u16* __restrict__ w2T,
    const float* __restrict__ bo) {
  __shared__ __align__(16) char sbuf[73728];
  u16* Xn = (u16*)sbuf;                 // 24 KB swizzled input
  u16* Hs = (u16*)(sbuf + 24576);       // 24 KB swizzled hidden (per-phase)
  u16* Wb0 = (u16*)(sbuf + 49152);      // 12 KB weight slice buf 0
  u16* Wb1 = (u16*)(sbuf + 61440);      // 12 KB weight slice buf 1
  float* Ef = (float*)sbuf;             // 48 KB fp32 epilogue (aliases Xn+Hs)
  const size_t T0 = (size_t)blockIdx.x * 64;
  const int t = threadIdx.x;
  const int w = t >> 6;
  const int lane = t & 63;
  const int mt = w & 3;
  const int half = w >> 2;

  {  // LN2: 8 lanes per token, 24 ch each
    const int tok = t >> 3;
    const int ch0 = (t & 7) * 24;
    const float* xp = out + (T0 + tok) * 192 + ch0;
    float v[24];
    float s = 0.f, sq = 0.f;
#pragma unroll
    for (int q = 0; q < 6; ++q) {
      const float4 f4 = *(const float4*)(xp + q * 4);
      v[q * 4 + 0] = f4.x; v[q * 4 + 1] = f4.y;
      v[q * 4 + 2] = f4.z; v[q * 4 + 3] = f4.w;
    }
#pragma unroll
    for (int q = 0; q < 24; ++q) { s += v[q]; sq += v[q] * v[q]; }
#pragma unroll
    for (int msk = 1; msk < 8; msk <<= 1) {
      s += __shfl_xor(s, msk);
      sq += __shfl_xor(sq, msk);
    }
    const float mean = s * (1.f / 192.f);
    const float var = sq * (1.f / 192.f) - mean * mean;
    const float rstd = rsqrtf(var + 1e-5f);
#pragma unroll
    for (int q = 0; q < 12; ++q) {
      const int ch = ch0 + q * 2;
      const float a0 = (v[q * 2] - mean) * rstd * g2[ch] + bn2[ch];
      const float a1 = (v[q * 2 + 1] - mean) * rstd * g2[ch + 1] + bn2[ch + 1];
      const unsigned int pk = (unsigned int)f2bf(a0) | ((unsigned int)f2bf(a1) << 16);
      const int cb = (ch << 1) ^ ((tok & 7) << 4);
      *(unsigned int*)&Xn[tok * 192 + (cb >> 1)] = pk;
    }
  }

  f32x4 acc2[6];
#pragma unroll
  for (int p = 0; p < 6; ++p) acc2[p] = vzero();
  int cur = 0;

  // prologue: stage fc1 ph0 kk0
  stage768_w8(w1T, 0, Wb0, w, lane);

  for (int ph = 0; ph < 4; ++ph) {
    // ---- fc1: 192 cols, K=192 ----
    f32x4 acc1[6];
#pragma unroll
    for (int p = 0; p < 6; ++p) acc1[p] = vzero();
#pragma unroll
    for (int kk = 0; kk < 6; ++kk) {
      __syncthreads();  // Wb[cur] ready; Xn ready on first iter
      u16* nxtW = cur ? Wb0 : Wb1;
      if (kk < 5) stage768_w8(w1T, ph * 6 + kk + 1, nxtW, w, lane);
      else        stage768_w8(w2T, ph * 6, nxtW, w, lane);
      const short8 a = ldsA(Xn, 192, mt << 4, kk << 5, lane);
      const u16* curW = cur ? Wb1 : Wb0;
#pragma unroll
      for (int p = 0; p < 6; ++p)
        acc1[p] = MFMA(a, ldsB(curW, half * 6 + p, lane), acc1[p]);
      cur ^= 1;
    }
    // ---- GELU -> Hs ----
#pragma unroll
    for (int p = 0; p < 6; ++p) {
      const int lcol = ((half * 6 + p) << 4) + (lane & 15);
      const float bias = b1[ph * 192 + lcol];
#pragma unroll
      for (int i = 0; i < 4; ++i) {
        const int r = (mt << 4) + ((lane >> 4) << 2) + i;
        const float hv = acc1[p][i] + bias;
        const float ge = gelu_f(hv);
        const int cb = (lcol << 1) ^ ((r & 7) << 4);
        Hs[r * 192 + (cb >> 1)] = f2bf(ge);
      }
    }
    // ---- fc2 partial: K slice [ph*192, +192), acc2 persists ----
#pragma unroll
    for (int kk = 0; kk < 6; ++kk) {
      __syncthreads();  // Hs visible (first iter) + Wb[cur] ready
      u16* nxtW = cur ? Wb0 : Wb1;
      if (kk < 5)      stage768_w8(w2T, ph * 6 + kk + 1, nxtW, w, lane);
      else if (ph < 3) stage768_w8(w1T, (ph + 1) * 6, nxtW, w, lane);
      const short8 a = ldsA(Hs, 192, mt << 4, kk << 5, lane);
      const u16* curW = cur ? Wb1 : Wb0;
#pragma unroll
      for (int p = 0; p < 6; ++p)
        acc2[p] = MFMA(a, ldsB(curW, half * 6 + p, lane), acc2[p]);
      cur ^= 1;
    }
  }

  // ---- epilogue: fp32 acc2 (no bias) -> Ef, then ((out+acc2)+bias) RMW ----
  __syncthreads();  // all fc2 reads of Hs/Wb done
#pragma unroll
  for (int p = 0; p < 6; ++p) {
    const int col = ((half * 6 + p) << 4) + (lane & 15);
#pragma unroll
    for (int i = 0; i < 4; ++i) {
      const int r = (mt << 4) + ((lane >> 4) << 2) + i;
      Ef[r * 192 + (col ^ ((r & 7) << 2))] = acc2[p][i];
    }
  }
  __syncthreads();
  {
    const int tok = t >> 3;
    const int ch0 = (t & 7) * 24;
    float* op = out + (T0 + tok) * 192 + ch0;
    const float* erow = Ef + tok * 192;
    const int swz = (tok & 7) << 2;
#pragma unroll
    for (int q = 0; q < 6; ++q) {
      const float4 ov = *(const float4*)(erow + ((ch0 + q * 4) ^ swz));
      const float4 bv = *(const float4*)(bo + ch0 + q * 4);
      float4 xv = *(const float4*)(op + q * 4);
      xv.x = (xv.x + ov.x) + bv.x;
      xv.y = (xv.y + ov.y) + bv.y;
      xv.z = (xv.z + ov.z) + bv.z;
      xv.w = (xv.w + ov.w) + bv.w;
      *(float4*)(op + q * 4) = xv;
    }
  }
}

// ---------------------------------------------------------------------------
extern "C" void kernel_launch(void* const* d_in, const int* in_sizes, int n_in,
                              void* d_out, int out_size, void* d_ws, size_t ws_size,
                              hipStream_t stream) {
  const float* x    = (const float*)d_in[0];
  const float* n1g  = (const float*)d_in[1];
  const float* n1b  = (const float*)d_in[2];
  const float* qkvw = (const float*)d_in[3];
  const float* qkvb = (const float*)d_in[4];
  const float* rpb  = (const float*)d_in[5];
  const float* pw   = (const float*)d_in[6];
  const float* pb   = (const float*)d_in[7];
  const float* n2g  = (const float*)d_in[8];
  const float* n2b  = (const float*)d_in[9];
  const float* w1   = (const float*)d_in[10];
  const float* b1   = (const float*)d_in[11];
  const float* w2   = (const float*)d_in[12];
  const float* b2   = (const float*)d_in[13];
  float* out = (float*)d_out;

  u16* hw    = (u16*)d_ws;                       // 131072*192 bf16 = 50.3 MB
  u16* wqkvT = hw + (size_t)131072 * 192;        // chunk-ordered [6][4][576][8]
  u16* projT = wqkvT + 576 * 192;                // chunk-ordered [6][4][192][8]
  u16* w1T   = projT + 192 * 192;                // chunk-ordered [4][6][4][192][8]
  u16* w2T   = w1T + 768 * 192;                  // chunk-ordered [4][6][4][192][8]

  prep_kernel<<<576, 256, 0, stream>>>(qkvw, pw, w1, w2, wqkvT, projT, w1T, w2T);
  attn_kernel<<<2048, 512, 0, stream>>>(x, n1g, n1b, wqkvT, qkvb, rpb, hw);
  proj_kernel<<<2048, 256, 0, stream>>>(hw, projT, pb, x, out);
  mlp_kernel<<<2048, 512, 0, stream>>>(out, n2g, n2b, w1T, b1, w2T, b2);
}

// Round 20
// 393.089 us; speedup vs baseline: 1.0410x; 1.0410x over previous
//
#include <hip/hip_runtime.h>
#include <math.h>

typedef float f32x4 __attribute__((ext_vector_type(4)));
typedef short short8 __attribute__((ext_vector_type(8)));
typedef unsigned short u16;

#define BB 32
#define CC 192
#define HEADS 6
#define NN 64
#define HID 768
#define NTOK (BB * 64 * 64)
#define SCALE 0.17677669529663687f

#define MFMA(a, b, c) __builtin_amdgcn_mfma_f32_16x16x32_bf16(a, b, c, 0, 0, 0)
// direct global->LDS 16B async copy: per-lane global src, wave-uniform LDS base
#define GLL16(g, l)                                                            \
  __builtin_amdgcn_global_load_lds(                                            \
      (const __attribute__((address_space(1))) void*)(g),                      \
      (__attribute__((address_space(3))) void*)(l), 16, 0, 0)

__device__ __forceinline__ u16 f2bf(float f) {
  union { float f; unsigned int u; } cv;
  cv.f = f;
  unsigned int u = cv.u;
  u += 0x7fffu + ((u >> 16) & 1u);
  return (u16)(u >> 16);
}

__device__ __forceinline__ f32x4 vzero() {
  f32x4 v;
  v[0] = 0.f; v[1] = 0.f; v[2] = 0.f; v[3] = 0.f;
  return v;
}

// exact GELU via Abramowitz-Stegun 7.1.26 erf (|eps|<=1.5e-7)
__device__ __forceinline__ float gelu_f(float x) {
  const float z = 0.70710678118654752f * x;
  const float az = fabsf(z);
  const float tt = __builtin_amdgcn_rcpf(1.0f + 0.3275911f * az);
  const float e = __expf(-az * az);
  float poly = 1.061405429f;
  poly = poly * tt - 1.453152027f;
  poly = poly * tt + 1.421413741f;
  poly = poly * tt - 0.284496736f;
  poly = poly * tt + 0.254829592f;
  float er = 1.0f - poly * tt * e;  // erf(az)
  er = z < 0.f ? -er : er;
  return 0.5f * x * (1.0f + er);
}

// A-style fragment read from swizzled LDS bf16 matrix. pitch in elements.
__device__ __forceinline__ short8 ldsA(const u16* M, int pitch, int r0, int k0, int lane) {
  const int r = r0 + (lane & 15);
  const int cb = ((k0 + ((lane >> 4) << 3)) << 1) ^ ((r & 7) << 4);
  return *(const short8*)(M + r * pitch + (cb >> 1));
}

// B fragment from staged LDS slice [kc][n][8] (n-width = pitch chunks of 192)
__device__ __forceinline__ short8 ldsB(const u16* Wb, int col16, int lane) {
  return *(const short8*)(Wb + (((lane >> 4) * 192) + (col16 << 4) + (lane & 15)) * 8);
}

// ---------------------------------------------------------------------------
// K0: convert weights to bf16 tables in STAGING-CHUNK order, plus the fused
// bias+mask table biasTab[cls][h][n][m] fp32, cls=(wr==7)*2+(wc==7).
// Unmasked entries hold the EXACT rpb value (bit-identical add path to r16);
// masked entries hold rpb-100 (weights underflow to 0 either way).
// ---------------------------------------------------------------------------
__global__ __launch_bounds__(256) void prep_kernel(
    const float* __restrict__ qkvw, const float* __restrict__ pw,
    const float* __restrict__ w1, const float* __restrict__ w2,
    const float* __restrict__ rpb,
    u16* __restrict__ wqkvT, u16* __restrict__ projT,
    u16* __restrict__ w1T, u16* __restrict__ w2T,
    float* __restrict__ biasTab) {
  const int id = blockIdx.x * 256 + threadIdx.x;
  if (id < 576 * 192) {  // wqkvT: [kk 0..5][kc 0..3][n 0..575][8]
    const int e = id & 7;
    const int c = id >> 3;
    const int n = c % 576;
    const int q = c / 576;             // 0..23
    const int kk = q >> 2, kc = q & 3;
    const int k = kk * 32 + kc * 8 + e;
    wqkvT[id] = f2bf(qkvw[k * 576 + n]);
  }
  if (id < 192 * 192) {  // projT: [kk 0..5][kc 0..3][n 0..191][8]
    const int e = id & 7;
    const int c = id >> 3;
    const int n = c % 192;
    const int q = c / 192;             // 0..23
    const int kk = q >> 2, kc = q & 3;
    const int k = kk * 32 + kc * 8 + e;
    projT[id] = f2bf(pw[k * 192 + n]);
  }
  if (id < 768 * 192) {  // w1T: [ph 0..3][kk 0..5][kc 0..3][n 0..191][8]
    const int e = id & 7;
    const int c = id >> 3;
    const int n = c % 192;
    const int q = c / 192;             // 0..95
    const int ph = q / 24, r = q % 24;
    const int kk = r >> 2, kc = r & 3;
    const int k = kk * 32 + kc * 8 + e;        // input channel
    w1T[id] = f2bf(w1[k * 768 + ph * 192 + n]);
  }
  if (id < 192 * 768) {  // w2T: [ph 0..3][kk 0..5][kc 0..3][n 0..191][8]
    const int e = id & 7;
    const int c = id >> 3;
    const int n = c % 192;
    const int q = c / 192;
    const int ph = q / 24, r = q % 24;
    const int kk = r >> 2, kc = r & 3;
    const int k = ph * 192 + kk * 32 + kc * 8 + e;  // hidden channel
    w2T[id] = f2bf(w2[k * 192 + n]);
  }
  if (id < 4 * HEADS * 64 * 64) {  // biasTab
    const int m = id & 63;
    const int n = (id >> 6) & 63;
    const int h = (id >> 12) % HEADS;
    const int cls = id / (HEADS * 4096);
    const int i1 = n >> 3, j1 = n & 7;
    const int i2 = m >> 3, j2 = m & 7;
    float v = rpb[((i1 - i2 + 7) * 15 + (j1 - j2 + 7)) * HEADS + h];
    const int rl1 = (cls & 2) ? (i1 < 4 ? 1 : 2) : 0;
    const int cl1 = (cls & 1) ? (j1 < 4 ? 1 : 2) : 0;
    const int rl2 = (cls & 2) ? (i2 < 4 ? 1 : 2) : 0;
    const int cl2 = (cls & 1) ? (j2 < 4 ? 1 : 2) : 0;
    if (rl1 * 3 + cl1 != rl2 * 3 + cl2) v -= 100.0f;
    biasTab[id] = v;
  }
}

// stage a 768-chunk (12 KB) slice via global_load_lds; 512-thread block
__device__ __forceinline__ void stage768_w8(const u16* tbl, int slice,
                                            u16* dst, int w, int lane) {
  const u16* base = tbl + ((size_t)slice * 768) * 8;
  GLL16(base + (w * 64 + lane) * 8, dst + (w * 64) * 8);
  if (w < 4) GLL16(base + (512 + w * 64 + lane) * 8, dst + (512 + w * 64) * 8);
}

// ---------------------------------------------------------------------------
// K2: fused LN1 + shift + windowed attention. (r16 structure; score bias via
// biasTab lookup + VALU add — bit-equal to r16 for all softmax-relevant values)
// ---------------------------------------------------------------------------
__global__ __launch_bounds__(512) void attn_kernel(
    const float* __restrict__ x, const float* __restrict__ n1g,
    const float* __restrict__ n1b, const u16* __restrict__ wqkvT,
    const float* __restrict__ qkvb, const float* __restrict__ biasTab,
    u16* __restrict__ hw) {
  __shared__ u16 Xs[64 * 192];
  __shared__ u16 Qs[64 * 192];
  __shared__ u16 Ks[64 * 192];
  __shared__ u16 Vt[192 * 64];     // [channel][token]
  __shared__ u16 Pb[2][64 * 64];
  __shared__ u16 Wq[4 * 576 * 8];  // 36 KB, [kc][n][8] for current K-step

  const int g = blockIdx.x;
  const int t = threadIdx.x;
  const int w = t >> 6;
  const int lane = t & 63;
  const int b = g >> 6;
  const int wr = (g >> 3) & 7, wc = g & 7;
  const int cls = (((wr == 7) ? 2 : 0) | ((wc == 7) ? 1 : 0));
  u16* win = hw + (size_t)g * (64 * 192);

  // ---- LN1 + cyclic shift gather -> Xs (swizzled). 8 lanes per token. ----
  {
    const int n = t >> 3;
    const int ch0 = (t & 7) * 24;
    const int sr = ((wr << 3) + (n >> 3) + 4) & 63;
    const int sc = ((wc << 3) + (n & 7) + 4) & 63;
    const float* xp = x + ((size_t)b * 4096 + sr * 64 + sc) * 192 + ch0;
    float v[24];
    float s = 0.f, sq = 0.f;
#pragma unroll
    for (int q = 0; q < 6; ++q) {
      const float4 f4 = *(const float4*)(xp + q * 4);
      v[q * 4 + 0] = f4.x; v[q * 4 + 1] = f4.y;
      v[q * 4 + 2] = f4.z; v[q * 4 + 3] = f4.w;
    }
#pragma unroll
    for (int q = 0; q < 24; ++q) { s += v[q]; sq += v[q] * v[q]; }
#pragma unroll
    for (int msk = 1; msk < 8; msk <<= 1) {
      s += __shfl_xor(s, msk);
      sq += __shfl_xor(sq, msk);
    }
    const float mean = s * (1.f / 192.f);
    const float var = sq * (1.f / 192.f) - mean * mean;
    const float rstd = rsqrtf(var + 1e-5f);
#pragma unroll
    for (int q = 0; q < 12; ++q) {
      const int ch = ch0 + q * 2;
      const float a0 = (v[q * 2] - mean) * rstd * n1g[ch] + n1b[ch];
      const float a1 = (v[q * 2 + 1] - mean) * rstd * n1g[ch + 1] + n1b[ch + 1];
      const unsigned int pk = (unsigned int)f2bf(a0) | ((unsigned int)f2bf(a1) << 16);
      const int cb = (ch << 1) ^ ((n & 7) << 4);
      *(unsigned int*)&Xs[n * 192 + (cb >> 1)] = pk;
    }
  }

  // ---- QKV GEMM: 64x192 @ 192x576, weights gll-staged per K-step ----
  const int ntbeg = (w < 4) ? w * 5 : 20 + (w - 4) * 4;
  const int ntcnt = (w < 4) ? 5 : 4;
  f32x4 acc[5][4];
#pragma unroll
  for (int p = 0; p < 5; ++p)
#pragma unroll
    for (int m = 0; m < 4; ++m) acc[p][m] = vzero();

  for (int kk = 0; kk < 6; ++kk) {
    {  // stage 2304 chunks = 36 gll issues
      const u16* src = wqkvT + ((size_t)kk * 2304) * 8;
#pragma unroll
      for (int j = 0; j < 4; ++j) {
        const int cb0 = (j * 8 + w) * 64;
        GLL16(src + (cb0 + lane) * 8, Wq + cb0 * 8);
      }
      if (w < 4) {
        const int cb0 = (32 + w) * 64;
        GLL16(src + (cb0 + lane) * 8, Wq + cb0 * 8);
      }
    }
    __syncthreads();  // drain gll (and Xs on first iter)
    short8 a[4];
#pragma unroll
    for (int m = 0; m < 4; ++m) a[m] = ldsA(Xs, 192, m << 4, kk << 5, lane);
#pragma unroll
    for (int p = 0; p < 5; ++p) {
      int nt = ntbeg + p;
      if (nt > 35) nt = 35;  // waves 4-7 duplicate last tile (discarded)
      const short8 bfr = *(const short8*)(
          Wq + (((lane >> 4) * 576) + (nt << 4) + (lane & 15)) * 8);
#pragma unroll
      for (int m = 0; m < 4; ++m) acc[p][m] = MFMA(a[m], bfr, acc[p][m]);
    }
    __syncthreads();  // all reads done before next stage overwrites Wq
  }

#pragma unroll
  for (int p = 0; p < 5; ++p) {
    if (p < ntcnt) {
      const int cg = ((ntbeg + p) << 4) + (lane & 15);
      const float bias = qkvb[cg];
#pragma unroll
      for (int m = 0; m < 4; ++m) {
#pragma unroll
        for (int i = 0; i < 4; ++i) {
          const int r = (m << 4) + ((lane >> 4) << 2) + i;
          const float val = acc[p][m][i] + bias;
          if (cg < 192) {
            const int cb = (cg << 1) ^ ((r & 7) << 4);
            Qs[r * 192 + (cb >> 1)] = f2bf(val * SCALE);
          } else if (cg < 384) {
            const int cb = ((cg - 192) << 1) ^ ((r & 7) << 4);
            Ks[r * 192 + (cb >> 1)] = f2bf(val);
          } else {
            const int vc = cg - 384;
            const int cb = (r << 1) ^ ((vc & 7) << 4);
            Vt[vc * 64 + (cb >> 1)] = f2bf(val);
          }
        }
      }
    }
  }
  __syncthreads();

  // ---- per-head: scores -> +bias(table) -> in-reg softmax -> PV ----
  const int s = w >> 2;
  const int mt = w & 3;
  u16* P = Pb[s];
  const int cbase = lane & 15;
  for (int hh = 0; hh < 3; ++hh) {
    const int h = s * 3 + hh;
    const float* bt = biasTab + (((size_t)cls * HEADS + h) << 12);
    const short8 aq = ldsA(Qs, 192, mt << 4, h << 5, lane);
    f32x4 d[4];
#pragma unroll
    for (int kb = 0; kb < 4; ++kb) {
      const short8 bk = ldsA(Ks, 192, kb << 4, h << 5, lane);
      d[kb] = MFMA(aq, bk, vzero());
      const int c = (kb << 4) + cbase;
#pragma unroll
      for (int i = 0; i < 4; ++i) {
        const int r = (mt << 4) + ((lane >> 4) << 2) + i;
        d[kb][i] += bt[r * 64 + c];
      }
    }
    // in-register softmax: row r spread over the 16-lane group (lane&15)
    float mx[4], sum[4];
#pragma unroll
    for (int i = 0; i < 4; ++i) {
      mx[i] = fmaxf(fmaxf(d[0][i], d[1][i]), fmaxf(d[2][i], d[3][i]));
    }
#pragma unroll
    for (int msk = 1; msk < 16; msk <<= 1) {
#pragma unroll
      for (int i = 0; i < 4; ++i) mx[i] = fmaxf(mx[i], __shfl_xor(mx[i], msk));
    }
#pragma unroll
    for (int i = 0; i < 4; ++i) sum[i] = 0.f;
#pragma unroll
    for (int kb = 0; kb < 4; ++kb) {
#pragma unroll
      for (int i = 0; i < 4; ++i) {
        const float e = __expf(d[kb][i] - mx[i]);
        d[kb][i] = e;
        sum[i] += e;
      }
    }
#pragma unroll
    for (int msk = 1; msk < 16; msk <<= 1) {
#pragma unroll
      for (int i = 0; i < 4; ++i) sum[i] += __shfl_xor(sum[i], msk);
    }
#pragma unroll
    for (int kb = 0; kb < 4; ++kb) {
      const int c = (kb << 4) + cbase;
#pragma unroll
      for (int i = 0; i < 4; ++i) {
        const int r = (mt << 4) + ((lane >> 4) << 2) + i;
        const int cb = (c << 1) ^ ((r & 7) << 4);
        P[r * 64 + (cb >> 1)] = f2bf(d[kb][i] / sum[i]);
      }
    }
    // PV: O rows 16mt..+15, cols h*32 + nb*16 (reads only this wave's P rows)
#pragma unroll
    for (int nb = 0; nb < 2; ++nb) {
      f32x4 o = vzero();
#pragma unroll
      for (int ks = 0; ks < 2; ++ks) {
        const short8 ap = ldsA(P, 64, mt << 4, ks << 5, lane);
        const short8 bv = ldsA(Vt, 64, (h << 5) + (nb << 4), ks << 5, lane);
        o = MFMA(ap, bv, o);
      }
      const int c = (h << 5) + (nb << 4) + (lane & 15);
#pragma unroll
      for (int i = 0; i < 4; ++i) {
        const int r = (mt << 4) + ((lane >> 4) << 2) + i;
        win[r * 192 + c] = f2bf(o[i]);
      }
    }
  }
}

// ---------------------------------------------------------------------------
// K3: proj GEMM (gll-staged dbuf) + bias + reverse shift scatter + residual.
// (r16 verbatim)
// ---------------------------------------------------------------------------
__global__ __launch_bounds__(256) void proj_kernel(
    const u16* __restrict__ hw, const u16* __restrict__ projT,
    const float* __restrict__ pb, const float* __restrict__ x,
    float* __restrict__ out) {
  __shared__ __align__(16) char sbuf[49152];
  u16* Os = (u16*)sbuf;                 // 24 KB input tile
  u16* Wp0 = (u16*)(sbuf + 24576);      // 12 KB weight slice buf 0
  u16* Wp1 = (u16*)(sbuf + 36864);      // 12 KB weight slice buf 1
  float* Ef = (float*)sbuf;             // 48 KB fp32 epilogue (aliases all)
  const int g = blockIdx.x;
  const int t = threadIdx.x;
  const int w = t >> 6;
  const int lane = t & 63;
  const int b_ = g >> 6;
  const int wr = (g >> 3) & 7, wc = g & 7;
  const u16* win = hw + (size_t)g * (64 * 192);
#pragma unroll
  for (int u = 0; u < 6; ++u) {
    const int d = (t * 6 + u) << 4;
    const int row = d / 384;
    const int cb = d - row * 384;
    const short8 v = *(const short8*)((const char*)win + d);
    *(short8*)((char*)Os + row * 384 + (cb ^ ((row & 7) << 4))) = v;
  }
  // prologue stage kk=0 (3 gll issues per wave)
#pragma unroll
  for (int j = 0; j < 3; ++j) {
    const int cb0 = (j * 4 + w) * 64;
    GLL16(projT + (cb0 + lane) * 8, Wp0 + cb0 * 8);
  }
  int cur = 0;
  f32x4 acc[12];
#pragma unroll
  for (int q = 0; q < 12; ++q) acc[q] = vzero();
  for (int kk = 0; kk < 6; ++kk) {
    __syncthreads();  // Os + Wp[cur] ready
    if (kk < 5) {
      const u16* src = projT + ((size_t)(kk + 1) * 768) * 8;
      u16* dstW = cur ? Wp0 : Wp1;
#pragma unroll
      for (int j = 0; j < 3; ++j) {
        const int cb0 = (j * 4 + w) * 64;
        GLL16(src + (cb0 + lane) * 8, dstW + cb0 * 8);
      }
    }
    const short8 a = ldsA(Os, 192, w << 4, kk << 5, lane);
    const u16* curW = cur ? Wp1 : Wp0;
#pragma unroll
    for (int q = 0; q < 12; ++q) acc[q] = MFMA(a, ldsB(curW, q, lane), acc[q]);
    cur ^= 1;
  }
  __syncthreads();  // all Os/Wp reads done before Ef alias writes
  // collect fp32 acc (no bias) into Ef, float4-granule XOR swizzle
#pragma unroll
  for (int q = 0; q < 12; ++q) {
    const int col = (q << 4) + (lane & 15);
#pragma unroll
    for (int i = 0; i < 4; ++i) {
      const int r = (w << 4) + ((lane >> 4) << 2) + i;
      Ef[r * 192 + (col ^ ((r & 7) << 2))] = acc[q][i];
    }
  }
  __syncthreads();
  // cooperative coalesced RMW: 4 threads per token, 48 floats each
  {
    const int tok = t >> 2;
    const int c0 = (t & 3) * 48;
    const int dr = ((wr << 3) + (tok >> 3) + 4) & 63;
    const int dc = ((wc << 3) + (tok & 7) + 4) & 63;
    const size_t dst = ((size_t)b_ * 4096 + dr * 64 + dc) * 192 + c0;
    const float* erow = Ef + tok * 192;
    const int swz = (tok & 7) << 2;
#pragma unroll
    for (int j = 0; j < 12; ++j) {
      const float4 ov = *(const float4*)(erow + ((c0 + j * 4) ^ swz));
      const float4 bv = *(const float4*)(pb + c0 + j * 4);
      float4 xv = *(const float4*)(x + dst + j * 4);
      xv.x = (xv.x + ov.x) + bv.x;
      xv.y = (xv.y + ov.y) + bv.y;
      xv.z = (xv.z + ov.z) + bv.z;
      xv.w = (xv.w + ov.w) + bv.w;
      *(float4*)(out + dst + j * 4) = xv;
    }
  }
}

// ---------------------------------------------------------------------------
// K4: LN2 + fc1 + GELU(A&S) + fc2 + residual. (r16 verbatim)
// ---------------------------------------------------------------------------
__global__ __launch_bounds__(512, 4) void mlp_kernel(
    float* __restrict__ out, const float* __restrict__ g2,
    const float* __restrict__ bn2, const u16* __restrict__ w1T,
    const float* __restrict__ b1, const u16* __restrict__ w2T,
    const float* __restrict__ bo) {
  __shared__ __align__(16) char sbuf[73728];
  u16* Xn = (u16*)sbuf;                 // 24 KB swizzled input
  u16* Hs = (u16*)(sbuf + 24576);       // 24 KB swizzled hidden (per-phase)
  u16* Wb0 = (u16*)(sbuf + 49152);      // 12 KB weight slice buf 0
  u16* Wb1 = (u16*)(sbuf + 61440);      // 12 KB weight slice buf 1
  float* Ef = (float*)sbuf;             // 48 KB fp32 epilogue (aliases Xn+Hs)
  const size_t T0 = (size_t)blockIdx.x * 64;
  const int t = threadIdx.x;
  const int w = t >> 6;
  const int lane = t & 63;
  const int mt = w & 3;
  const int half = w >> 2;

  {  // LN2: 8 lanes per token, 24 ch each
    const int tok = t >> 3;
    const int ch0 = (t & 7) * 24;
    const float* xp = out + (T0 + tok) * 192 + ch0;
    float v[24];
    float s = 0.f, sq = 0.f;
#pragma unroll
    for (int q = 0; q < 6; ++q) {
      const float4 f4 = *(const float4*)(xp + q * 4);
      v[q * 4 + 0] = f4.x; v[q * 4 + 1] = f4.y;
      v[q * 4 + 2] = f4.z; v[q * 4 + 3] = f4.w;
    }
#pragma unroll
    for (int q = 0; q < 24; ++q) { s += v[q]; sq += v[q] * v[q]; }
#pragma unroll
    for (int msk = 1; msk < 8; msk <<= 1) {
      s += __shfl_xor(s, msk);
      sq += __shfl_xor(sq, msk);
    }
    const float mean = s * (1.f / 192.f);
    const float var = sq * (1.f / 192.f) - mean * mean;
    const float rstd = rsqrtf(var + 1e-5f);
#pragma unroll
    for (int q = 0; q < 12; ++q) {
      const int ch = ch0 + q * 2;
      const float a0 = (v[q * 2] - mean) * rstd * g2[ch] + bn2[ch];
      const float a1 = (v[q * 2 + 1] - mean) * rstd * g2[ch + 1] + bn2[ch + 1];
      const unsigned int pk = (unsigned int)f2bf(a0) | ((unsigned int)f2bf(a1) << 16);
      const int cb = (ch << 1) ^ ((tok & 7) << 4);
      *(unsigned int*)&Xn[tok * 192 + (cb >> 1)] = pk;
    }
  }

  f32x4 acc2[6];
#pragma unroll
  for (int p = 0; p < 6; ++p) acc2[p] = vzero();
  int cur = 0;

  // prologue: stage fc1 ph0 kk0
  stage768_w8(w1T, 0, Wb0, w, lane);

  for (int ph = 0; ph < 4; ++ph) {
    // ---- fc1: 192 cols, K=192 ----
    f32x4 acc1[6];
#pragma unroll
    for (int p = 0; p < 6; ++p) acc1[p] = vzero();
#pragma unroll
    for (int kk = 0; kk < 6; ++kk) {
      __syncthreads();  // Wb[cur] ready; Xn ready on first iter
      u16* nxtW = cur ? Wb0 : Wb1;
      if (kk < 5) stage768_w8(w1T, ph * 6 + kk + 1, nxtW, w, lane);
      else        stage768_w8(w2T, ph * 6, nxtW, w, lane);
      const short8 a = ldsA(Xn, 192, mt << 4, kk << 5, lane);
      const u16* curW = cur ? Wb1 : Wb0;
#pragma unroll
      for (int p = 0; p < 6; ++p)
        acc1[p] = MFMA(a, ldsB(curW, half * 6 + p, lane), acc1[p]);
      cur ^= 1;
    }
    // ---- GELU -> Hs ----
#pragma unroll
    for (int p = 0; p < 6; ++p) {
      const int lcol = ((half * 6 + p) << 4) + (lane & 15);
      const float bias = b1[ph * 192 + lcol];
#pragma unroll
      for (int i = 0; i < 4; ++i) {
        const int r = (mt << 4) + ((lane >> 4) << 2) + i;
        const float hv = acc1[p][i] + bias;
        const float ge = gelu_f(hv);
        const int cb = (lcol << 1) ^ ((r & 7) << 4);
        Hs[r * 192 + (cb >> 1)] = f2bf(ge);
      }
    }
    // ---- fc2 partial: K slice [ph*192, +192), acc2 persists ----
#pragma unroll
    for (int kk = 0; kk < 6; ++kk) {
      __syncthreads();  // Hs visible (first iter) + Wb[cur] ready
      u16* nxtW = cur ? Wb0 : Wb1;
      if (kk < 5)      stage768_w8(w2T, ph * 6 + kk + 1, nxtW, w, lane);
      else if (ph < 3) stage768_w8(w1T, (ph + 1) * 6, nxtW, w, lane);
      const short8 a = ldsA(Hs, 192, mt << 4, kk << 5, lane);
      const u16* curW = cur ? Wb1 : Wb0;
#pragma unroll
      for (int p = 0; p < 6; ++p)
        acc2[p] = MFMA(a, ldsB(curW, half * 6 + p, lane), acc2[p]);
      cur ^= 1;
    }
  }

  // ---- epilogue: fp32 acc2 (no bias) -> Ef, then ((out+acc2)+bias) RMW ----
  __syncthreads();  // all fc2 reads of Hs/Wb done
#pragma unroll
  for (int p = 0; p < 6; ++p) {
    const int col = ((half * 6 + p) << 4) + (lane & 15);
#pragma unroll
    for (int i = 0; i < 4; ++i) {
      const int r = (mt << 4) + ((lane >> 4) << 2) + i;
      Ef[r * 192 + (col ^ ((r & 7) << 2))] = acc2[p][i];
    }
  }
  __syncthreads();
  {
    const int tok = t >> 3;
    const int ch0 = (t & 7) * 24;
    float* op = out + (T0 + tok) * 192 + ch0;
    const float* erow = Ef + tok * 192;
    const int swz = (tok & 7) << 2;
#pragma unroll
    for (int q = 0; q < 6; ++q) {
      const float4 ov = *(const float4*)(erow + ((ch0 + q * 4) ^ swz));
      const float4 bv = *(const float4*)(bo + ch0 + q * 4);
      float4 xv = *(const float4*)(op + q * 4);
      xv.x = (xv.x + ov.x) + bv.x;
      xv.y = (xv.y + ov.y) + bv.y;
      xv.z = (xv.z + ov.z) + bv.z;
      xv.w = (xv.w + ov.w) + bv.w;
      *(float4*)(op + q * 4) = xv;
    }
  }
}

// ---------------------------------------------------------------------------
extern "C" void kernel_launch(void* const* d_in, const int* in_sizes, int n_in,
                              void* d_out, int out_size, void* d_ws, size_t ws_size,
                              hipStream_t stream) {
  const float* x    = (const float*)d_in[0];
  const float* n1g  = (const float*)d_in[1];
  const float* n1b  = (const float*)d_in[2];
  const float* qkvw = (const float*)d_in[3];
  const float* qkvb = (const float*)d_in[4];
  const float* rpb  = (const float*)d_in[5];
  const float* pw   = (const float*)d_in[6];
  const float* pb   = (const float*)d_in[7];
  const float* n2g  = (const float*)d_in[8];
  const float* n2b  = (const float*)d_in[9];
  const float* w1   = (const float*)d_in[10];
  const float* b1   = (const float*)d_in[11];
  const float* w2   = (const float*)d_in[12];
  const float* b2   = (const float*)d_in[13];
  float* out = (float*)d_out;

  u16* hw    = (u16*)d_ws;                       // 131072*192 bf16 = 50.3 MB
  u16* wqkvT = hw + (size_t)131072 * 192;        // chunk-ordered [6][4][576][8]
  u16* projT = wqkvT + 576 * 192;                // chunk-ordered [6][4][192][8]
  u16* w1T   = projT + 192 * 192;                // chunk-ordered [4][6][4][192][8]
  u16* w2T   = w1T + 768 * 192;                  // chunk-ordered [4][6][4][192][8]
  float* biasTab = (float*)(w2T + (size_t)192 * 768);  // [4][6][64][64] fp32

  prep_kernel<<<576, 256, 0, stream>>>(qkvw, pw, w1, w2, rpb,
                                       wqkvT, projT, w1T, w2T, biasTab);
  attn_kernel<<<2048, 512, 0, stream>>>(x, n1g, n1b, wqkvT, qkvb, biasTab, hw);
  proj_kernel<<<2048, 256, 0, stream>>>(hw, projT, pb, x, out);
  mlp_kernel<<<2048, 512, 0, stream>>>(out, n2g, n2b, w1T, b1, w2T, b2);
}

// Round 21
// 393.075 us; speedup vs baseline: 1.0411x; 1.0000x over previous
//
#include <hip/hip_runtime.h>
#include <math.h>

typedef float f32x4 __attribute__((ext_vector_type(4)));
typedef short short8 __attribute__((ext_vector_type(8)));
typedef unsigned short u16;

#define BB 32
#define CC 192
#define HEADS 6
#define NN 64
#define HID 768
#define NTOK (BB * 64 * 64)
#define SCALE 0.17677669529663687f

#define MFMA(a, b, c) __builtin_amdgcn_mfma_f32_16x16x32_bf16(a, b, c, 0, 0, 0)
// direct global->LDS 16B async copy: per-lane global src, wave-uniform LDS base
#define GLL16(g, l)                                                            \
  __builtin_amdgcn_global_load_lds(                                            \
      (const __attribute__((address_space(1))) void*)(g),                      \
      (__attribute__((address_space(3))) void*)(l), 16, 0, 0)

__device__ __forceinline__ u16 f2bf(float f) {
  union { float f; unsigned int u; } cv;
  cv.f = f;
  unsigned int u = cv.u;
  u += 0x7fffu + ((u >> 16) & 1u);
  return (u16)(u >> 16);
}

__device__ __forceinline__ f32x4 vzero() {
  f32x4 v;
  v[0] = 0.f; v[1] = 0.f; v[2] = 0.f; v[3] = 0.f;
  return v;
}

// exact GELU via Abramowitz-Stegun 7.1.26 erf (|eps|<=1.5e-7)
__device__ __forceinline__ float gelu_f(float x) {
  const float z = 0.70710678118654752f * x;
  const float az = fabsf(z);
  const float tt = __builtin_amdgcn_rcpf(1.0f + 0.3275911f * az);
  const float e = __expf(-az * az);
  float poly = 1.061405429f;
  poly = poly * tt - 1.453152027f;
  poly = poly * tt + 1.421413741f;
  poly = poly * tt - 0.284496736f;
  poly = poly * tt + 0.254829592f;
  float er = 1.0f - poly * tt * e;  // erf(az)
  er = z < 0.f ? -er : er;
  return 0.5f * x * (1.0f + er);
}

// A-style fragment read from swizzled LDS bf16 matrix. pitch in elements.
__device__ __forceinline__ short8 ldsA(const u16* M, int pitch, int r0, int k0, int lane) {
  const int r = r0 + (lane & 15);
  const int cb = ((k0 + ((lane >> 4) << 3)) << 1) ^ ((r & 7) << 4);
  return *(const short8*)(M + r * pitch + (cb >> 1));
}

// B fragment from staged LDS slice [kc][n][8] (n-width = pitch chunks of 192)
__device__ __forceinline__ short8 ldsB(const u16* Wb, int col16, int lane) {
  return *(const short8*)(Wb + (((lane >> 4) * 192) + (col16 << 4) + (lane & 15)) * 8);
}

// ---------------------------------------------------------------------------
// K0: convert weights to bf16 tables in STAGING-CHUNK order, plus the fused
// bias+mask table biasTab[cls][h][n][m] fp32, cls=(wr==7)*2+(wc==7).
// Unmasked entries hold the EXACT rpb value (bit-identical add path to r16);
// masked entries hold rpb-100 (weights underflow to 0 either way).
// ---------------------------------------------------------------------------
__global__ __launch_bounds__(256) void prep_kernel(
    const float* __restrict__ qkvw, const float* __restrict__ pw,
    const float* __restrict__ w1, const float* __restrict__ w2,
    const float* __restrict__ rpb,
    u16* __restrict__ wqkvT, u16* __restrict__ projT,
    u16* __restrict__ w1T, u16* __restrict__ w2T,
    float* __restrict__ biasTab) {
  const int id = blockIdx.x * 256 + threadIdx.x;
  if (id < 576 * 192) {  // wqkvT: [kk 0..5][kc 0..3][n 0..575][8]
    const int e = id & 7;
    const int c = id >> 3;
    const int n = c % 576;
    const int q = c / 576;             // 0..23
    const int kk = q >> 2, kc = q & 3;
    const int k = kk * 32 + kc * 8 + e;
    wqkvT[id] = f2bf(qkvw[k * 576 + n]);
  }
  if (id < 192 * 192) {  // projT: [kk 0..5][kc 0..3][n 0..191][8]
    const int e = id & 7;
    const int c = id >> 3;
    const int n = c % 192;
    const int q = c / 192;             // 0..23
    const int kk = q >> 2, kc = q & 3;
    const int k = kk * 32 + kc * 8 + e;
    projT[id] = f2bf(pw[k * 192 + n]);
  }
  if (id < 768 * 192) {  // w1T: [ph 0..3][kk 0..5][kc 0..3][n 0..191][8]
    const int e = id & 7;
    const int c = id >> 3;
    const int n = c % 192;
    const int q = c / 192;             // 0..95
    const int ph = q / 24, r = q % 24;
    const int kk = r >> 2, kc = r & 3;
    const int k = kk * 32 + kc * 8 + e;        // input channel
    w1T[id] = f2bf(w1[k * 768 + ph * 192 + n]);
  }
  if (id < 192 * 768) {  // w2T: [ph 0..3][kk 0..5][kc 0..3][n 0..191][8]
    const int e = id & 7;
    const int c = id >> 3;
    const int n = c % 192;
    const int q = c / 192;
    const int ph = q / 24, r = q % 24;
    const int kk = r >> 2, kc = r & 3;
    const int k = ph * 192 + kk * 32 + kc * 8 + e;  // hidden channel
    w2T[id] = f2bf(w2[k * 192 + n]);
  }
  if (id < 4 * HEADS * 64 * 64) {  // biasTab
    const int m = id & 63;
    const int n = (id >> 6) & 63;
    const int h = (id >> 12) % HEADS;
    const int cls = id / (HEADS * 4096);
    const int i1 = n >> 3, j1 = n & 7;
    const int i2 = m >> 3, j2 = m & 7;
    float v = rpb[((i1 - i2 + 7) * 15 + (j1 - j2 + 7)) * HEADS + h];
    const int rl1 = (cls & 2) ? (i1 < 4 ? 1 : 2) : 0;
    const int cl1 = (cls & 1) ? (j1 < 4 ? 1 : 2) : 0;
    const int rl2 = (cls & 2) ? (i2 < 4 ? 1 : 2) : 0;
    const int cl2 = (cls & 1) ? (j2 < 4 ? 1 : 2) : 0;
    if (rl1 * 3 + cl1 != rl2 * 3 + cl2) v -= 100.0f;
    biasTab[id] = v;
  }
}

// stage a 768-chunk (12 KB) slice via global_load_lds; 512-thread block
__device__ __forceinline__ void stage768_w8(const u16* tbl, int slice,
                                            u16* dst, int w, int lane) {
  const u16* base = tbl + ((size_t)slice * 768) * 8;
  GLL16(base + (w * 64 + lane) * 8, dst + (w * 64) * 8);
  if (w < 4) GLL16(base + (512 + w * 64 + lane) * 8, dst + (512 + w * 64) * 8);
}

// ---------------------------------------------------------------------------
// K2: fused LN1 + shift + windowed attention. (r16 structure; score bias via
// biasTab lookup + VALU add — bit-equal to r16 for all softmax-relevant values)
// ---------------------------------------------------------------------------
__global__ __launch_bounds__(512) void attn_kernel(
    const float* __restrict__ x, const float* __restrict__ n1g,
    const float* __restrict__ n1b, const u16* __restrict__ wqkvT,
    const float* __restrict__ qkvb, const float* __restrict__ biasTab,
    u16* __restrict__ hw) {
  __shared__ u16 Xs[64 * 192];
  __shared__ u16 Qs[64 * 192];
  __shared__ u16 Ks[64 * 192];
  __shared__ u16 Vt[192 * 64];     // [channel][token]
  __shared__ u16 Pb[2][64 * 64];
  __shared__ u16 Wq[4 * 576 * 8];  // 36 KB, [kc][n][8] for current K-step

  const int g = blockIdx.x;
  const int t = threadIdx.x;
  const int w = t >> 6;
  const int lane = t & 63;
  const int b = g >> 6;
  const int wr = (g >> 3) & 7, wc = g & 7;
  const int cls = (((wr == 7) ? 2 : 0) | ((wc == 7) ? 1 : 0));
  u16* win = hw + (size_t)g * (64 * 192);

  // ---- LN1 + cyclic shift gather -> Xs (swizzled). 8 lanes per token. ----
  {
    const int n = t >> 3;
    const int ch0 = (t & 7) * 24;
    const int sr = ((wr << 3) + (n >> 3) + 4) & 63;
    const int sc = ((wc << 3) + (n & 7) + 4) & 63;
    const float* xp = x + ((size_t)b * 4096 + sr * 64 + sc) * 192 + ch0;
    float v[24];
    float s = 0.f, sq = 0.f;
#pragma unroll
    for (int q = 0; q < 6; ++q) {
      const float4 f4 = *(const float4*)(xp + q * 4);
      v[q * 4 + 0] = f4.x; v[q * 4 + 1] = f4.y;
      v[q * 4 + 2] = f4.z; v[q * 4 + 3] = f4.w;
    }
#pragma unroll
    for (int q = 0; q < 24; ++q) { s += v[q]; sq += v[q] * v[q]; }
#pragma unroll
    for (int msk = 1; msk < 8; msk <<= 1) {
      s += __shfl_xor(s, msk);
      sq += __shfl_xor(sq, msk);
    }
    const float mean = s * (1.f / 192.f);
    const float var = sq * (1.f / 192.f) - mean * mean;
    const float rstd = rsqrtf(var + 1e-5f);
#pragma unroll
    for (int q = 0; q < 12; ++q) {
      const int ch = ch0 + q * 2;
      const float a0 = (v[q * 2] - mean) * rstd * n1g[ch] + n1b[ch];
      const float a1 = (v[q * 2 + 1] - mean) * rstd * n1g[ch + 1] + n1b[ch + 1];
      const unsigned int pk = (unsigned int)f2bf(a0) | ((unsigned int)f2bf(a1) << 16);
      const int cb = (ch << 1) ^ ((n & 7) << 4);
      *(unsigned int*)&Xs[n * 192 + (cb >> 1)] = pk;
    }
  }

  // ---- QKV GEMM: 64x192 @ 192x576, weights gll-staged per K-step ----
  const int ntbeg = (w < 4) ? w * 5 : 20 + (w - 4) * 4;
  const int ntcnt = (w < 4) ? 5 : 4;
  f32x4 acc[5][4];
#pragma unroll
  for (int p = 0; p < 5; ++p)
#pragma unroll
    for (int m = 0; m < 4; ++m) acc[p][m] = vzero();

  for (int kk = 0; kk < 6; ++kk) {
    {  // stage 2304 chunks = 36 gll issues
      const u16* src = wqkvT + ((size_t)kk * 2304) * 8;
#pragma unroll
      for (int j = 0; j < 4; ++j) {
        const int cb0 = (j * 8 + w) * 64;
        GLL16(src + (cb0 + lane) * 8, Wq + cb0 * 8);
      }
      if (w < 4) {
        const int cb0 = (32 + w) * 64;
        GLL16(src + (cb0 + lane) * 8, Wq + cb0 * 8);
      }
    }
    __syncthreads();  // drain gll (and Xs on first iter)
    short8 a[4];
#pragma unroll
    for (int m = 0; m < 4; ++m) a[m] = ldsA(Xs, 192, m << 4, kk << 5, lane);
#pragma unroll
    for (int p = 0; p < 5; ++p) {
      int nt = ntbeg + p;
      if (nt > 35) nt = 35;  // waves 4-7 duplicate last tile (discarded)
      const short8 bfr = *(const short8*)(
          Wq + (((lane >> 4) * 576) + (nt << 4) + (lane & 15)) * 8);
#pragma unroll
      for (int m = 0; m < 4; ++m) acc[p][m] = MFMA(a[m], bfr, acc[p][m]);
    }
    __syncthreads();  // all reads done before next stage overwrites Wq
  }

#pragma unroll
  for (int p = 0; p < 5; ++p) {
    if (p < ntcnt) {
      const int cg = ((ntbeg + p) << 4) + (lane & 15);
      const float bias = qkvb[cg];
#pragma unroll
      for (int m = 0; m < 4; ++m) {
#pragma unroll
        for (int i = 0; i < 4; ++i) {
          const int r = (m << 4) + ((lane >> 4) << 2) + i;
          const float val = acc[p][m][i] + bias;
          if (cg < 192) {
            const int cb = (cg << 1) ^ ((r & 7) << 4);
            Qs[r * 192 + (cb >> 1)] = f2bf(val * SCALE);
          } else if (cg < 384) {
            const int cb = ((cg - 192) << 1) ^ ((r & 7) << 4);
            Ks[r * 192 + (cb >> 1)] = f2bf(val);
          } else {
            const int vc = cg - 384;
            const int cb = (r << 1) ^ ((vc & 7) << 4);
            Vt[vc * 64 + (cb >> 1)] = f2bf(val);
          }
        }
      }
    }
  }
  __syncthreads();

  // ---- per-head: scores -> +bias(table) -> in-reg softmax -> PV ----
  const int s = w >> 2;
  const int mt = w & 3;
  u16* P = Pb[s];
  const int cbase = lane & 15;
  for (int hh = 0; hh < 3; ++hh) {
    const int h = s * 3 + hh;
    const float* bt = biasTab + (((size_t)cls * HEADS + h) << 12);
    const short8 aq = ldsA(Qs, 192, mt << 4, h << 5, lane);
    f32x4 d[4];
#pragma unroll
    for (int kb = 0; kb < 4; ++kb) {
      const short8 bk = ldsA(Ks, 192, kb << 4, h << 5, lane);
      d[kb] = MFMA(aq, bk, vzero());
      const int c = (kb << 4) + cbase;
#pragma unroll
      for (int i = 0; i < 4; ++i) {
        const int r = (mt << 4) + ((lane >> 4) << 2) + i;
        d[kb][i] += bt[r * 64 + c];
      }
    }
    // in-register softmax: row r spread over the 16-lane group (lane&15)
    float mx[4], sum[4];
#pragma unroll
    for (int i = 0; i < 4; ++i) {
      mx[i] = fmaxf(fmaxf(d[0][i], d[1][i]), fmaxf(d[2][i], d[3][i]));
    }
#pragma unroll
    for (int msk = 1; msk < 16; msk <<= 1) {
#pragma unroll
      for (int i = 0; i < 4; ++i) mx[i] = fmaxf(mx[i], __shfl_xor(mx[i], msk));
    }
#pragma unroll
    for (int i = 0; i < 4; ++i) sum[i] = 0.f;
#pragma unroll
    for (int kb = 0; kb < 4; ++kb) {
#pragma unroll
      for (int i = 0; i < 4; ++i) {
        const float e = __expf(d[kb][i] - mx[i]);
        d[kb][i] = e;
        sum[i] += e;
      }
    }
#pragma unroll
    for (int msk = 1; msk < 16; msk <<= 1) {
#pragma unroll
      for (int i = 0; i < 4; ++i) sum[i] += __shfl_xor(sum[i], msk);
    }
#pragma unroll
    for (int kb = 0; kb < 4; ++kb) {
      const int c = (kb << 4) + cbase;
#pragma unroll
      for (int i = 0; i < 4; ++i) {
        const int r = (mt << 4) + ((lane >> 4) << 2) + i;
        const int cb = (c << 1) ^ ((r & 7) << 4);
        P[r * 64 + (cb >> 1)] = f2bf(d[kb][i] / sum[i]);
      }
    }
    // PV: O rows 16mt..+15, cols h*32 + nb*16 (reads only this wave's P rows)
#pragma unroll
    for (int nb = 0; nb < 2; ++nb) {
      f32x4 o = vzero();
#pragma unroll
      for (int ks = 0; ks < 2; ++ks) {
        const short8 ap = ldsA(P, 64, mt << 4, ks << 5, lane);
        const short8 bv = ldsA(Vt, 64, (h << 5) + (nb << 4), ks << 5, lane);
        o = MFMA(ap, bv, o);
      }
      const int c = (h << 5) + (nb << 4) + (lane & 15);
#pragma unroll
      for (int i = 0; i < 4; ++i) {
        const int r = (mt << 4) + ((lane >> 4) << 2) + i;
        win[r * 192 + c] = f2bf(o[i]);
      }
    }
  }
}

// ---------------------------------------------------------------------------
// K3: proj GEMM (gll-staged dbuf) + bias + reverse shift scatter + residual.
// (r16 verbatim)
// ---------------------------------------------------------------------------
__global__ __launch_bounds__(256) void proj_kernel(
    const u16* __restrict__ hw, const u16* __restrict__ projT,
    const float* __restrict__ pb, const float* __restrict__ x,
    float* __restrict__ out) {
  __shared__ __align__(16) char sbuf[49152];
  u16* Os = (u16*)sbuf;                 // 24 KB input tile
  u16* Wp0 = (u16*)(sbuf + 24576);      // 12 KB weight slice buf 0
  u16* Wp1 = (u16*)(sbuf + 36864);      // 12 KB weight slice buf 1
  float* Ef = (float*)sbuf;             // 48 KB fp32 epilogue (aliases all)
  const int g = blockIdx.x;
  const int t = threadIdx.x;
  const int w = t >> 6;
  const int lane = t & 63;
  const int b_ = g >> 6;
  const int wr = (g >> 3) & 7, wc = g & 7;
  const u16* win = hw + (size_t)g * (64 * 192);
#pragma unroll
  for (int u = 0; u < 6; ++u) {
    const int d = (t * 6 + u) << 4;
    const int row = d / 384;
    const int cb = d - row * 384;
    const short8 v = *(const short8*)((const char*)win + d);
    *(short8*)((char*)Os + row * 384 + (cb ^ ((row & 7) << 4))) = v;
  }
  // prologue stage kk=0 (3 gll issues per wave)
#pragma unroll
  for (int j = 0; j < 3; ++j) {
    const int cb0 = (j * 4 + w) * 64;
    GLL16(projT + (cb0 + lane) * 8, Wp0 + cb0 * 8);
  }
  int cur = 0;
  f32x4 acc[12];
#pragma unroll
  for (int q = 0; q < 12; ++q) acc[q] = vzero();
  for (int kk = 0; kk < 6; ++kk) {
    __syncthreads();  // Os + Wp[cur] ready
    if (kk < 5) {
      const u16* src = projT + ((size_t)(kk + 1) * 768) * 8;
      u16* dstW = cur ? Wp0 : Wp1;
#pragma unroll
      for (int j = 0; j < 3; ++j) {
        const int cb0 = (j * 4 + w) * 64;
        GLL16(src + (cb0 + lane) * 8, dstW + cb0 * 8);
      }
    }
    const short8 a = ldsA(Os, 192, w << 4, kk << 5, lane);
    const u16* curW = cur ? Wp1 : Wp0;
#pragma unroll
    for (int q = 0; q < 12; ++q) acc[q] = MFMA(a, ldsB(curW, q, lane), acc[q]);
    cur ^= 1;
  }
  __syncthreads();  // all Os/Wp reads done before Ef alias writes
  // collect fp32 acc (no bias) into Ef, float4-granule XOR swizzle
#pragma unroll
  for (int q = 0; q < 12; ++q) {
    const int col = (q << 4) + (lane & 15);
#pragma unroll
    for (int i = 0; i < 4; ++i) {
      const int r = (w << 4) + ((lane >> 4) << 2) + i;
      Ef[r * 192 + (col ^ ((r & 7) << 2))] = acc[q][i];
    }
  }
  __syncthreads();
  // cooperative coalesced RMW: 4 threads per token, 48 floats each
  {
    const int tok = t >> 2;
    const int c0 = (t & 3) * 48;
    const int dr = ((wr << 3) + (tok >> 3) + 4) & 63;
    const int dc = ((wc << 3) + (tok & 7) + 4) & 63;
    const size_t dst = ((size_t)b_ * 4096 + dr * 64 + dc) * 192 + c0;
    const float* erow = Ef + tok * 192;
    const int swz = (tok & 7) << 2;
#pragma unroll
    for (int j = 0; j < 12; ++j) {
      const float4 ov = *(const float4*)(erow + ((c0 + j * 4) ^ swz));
      const float4 bv = *(const float4*)(pb + c0 + j * 4);
      float4 xv = *(const float4*)(x + dst + j * 4);
      xv.x = (xv.x + ov.x) + bv.x;
      xv.y = (xv.y + ov.y) + bv.y;
      xv.z = (xv.z + ov.z) + bv.z;
      xv.w = (xv.w + ov.w) + bv.w;
      *(float4*)(out + dst + j * 4) = xv;
    }
  }
}

// ---------------------------------------------------------------------------
// K4: LN2 + fc1 + GELU(A&S) + fc2 + residual. (r16 verbatim)
// ---------------------------------------------------------------------------
__global__ __launch_bounds__(512, 4) void mlp_kernel(
    float* __restrict__ out, const float* __restrict__ g2,
    const float* __restrict__ bn2, const u16* __restrict__ w1T,
    const float* __restrict__ b1, const u16* __restrict__ w2T,
    const float* __restrict__ bo) {
  __shared__ __align__(16) char sbuf[73728];
  u16* Xn = (u16*)sbuf;                 // 24 KB swizzled input
  u16* Hs = (u16*)(sbuf + 24576);       // 24 KB swizzled hidden (per-phase)
  u16* Wb0 = (u16*)(sbuf + 49152);      // 12 KB weight slice buf 0
  u16* Wb1 = (u16*)(sbuf + 61440);      // 12 KB weight slice buf 1
  float* Ef = (float*)sbuf;             // 48 KB fp32 epilogue (aliases Xn+Hs)
  const size_t T0 = (size_t)blockIdx.x * 64;
  const int t = threadIdx.x;
  const int w = t >> 6;
  const int lane = t & 63;
  const int mt = w & 3;
  const int half = w >> 2;

  {  // LN2: 8 lanes per token, 24 ch each
    const int tok = t >> 3;
    const int ch0 = (t & 7) * 24;
    const float* xp = out + (T0 + tok) * 192 + ch0;
    float v[24];
    float s = 0.f, sq = 0.f;
#pragma unroll
    for (int q = 0; q < 6; ++q) {
      const float4 f4 = *(const float4*)(xp + q * 4);
      v[q * 4 + 0] = f4.x; v[q * 4 + 1] = f4.y;
      v[q * 4 + 2] = f4.z; v[q * 4 + 3] = f4.w;
    }
#pragma unroll
    for (int q = 0; q < 24; ++q) { s += v[q]; sq += v[q] * v[q]; }
#pragma unroll
    for (int msk = 1; msk < 8; msk <<= 1) {
      s += __shfl_xor(s, msk);
      sq += __shfl_xor(sq, msk);
    }
    const float mean = s * (1.f / 192.f);
    const float var = sq * (1.f / 192.f) - mean * mean;
    const float rstd = rsqrtf(var + 1e-5f);
#pragma unroll
    for (int q = 0; q < 12; ++q) {
      const int ch = ch0 + q * 2;
      const float a0 = (v[q * 2] - mean) * rstd * g2[ch] + bn2[ch];
      const float a1 = (v[q * 2 + 1] - mean) * rstd * g2[ch + 1] + bn2[ch + 1];
      const unsigned int pk = (unsigned int)f2bf(a0) | ((unsigned int)f2bf(a1) << 16);
      const int cb = (ch << 1) ^ ((tok & 7) << 4);
      *(unsigned int*)&Xn[tok * 192 + (cb >> 1)] = pk;
    }
  }

  f32x4 acc2[6];
#pragma unroll
  for (int p = 0; p < 6; ++p) acc2[p] = vzero();
  int cur = 0;

  // prologue: stage fc1 ph0 kk0
  stage768_w8(w1T, 0, Wb0, w, lane);

  for (int ph = 0; ph < 4; ++ph) {
    // ---- fc1: 192 cols, K=192 ----
    f32x4 acc1[6];
#pragma unroll
    for (int p = 0; p < 6; ++p) acc1[p] = vzero();
#pragma unroll
    for (int kk = 0; kk < 6; ++kk) {
      __syncthreads();  // Wb[cur] ready; Xn ready on first iter
      u16* nxtW = cur ? Wb0 : Wb1;
      if (kk < 5) stage768_w8(w1T, ph * 6 + kk + 1, nxtW, w, lane);
      else        stage768_w8(w2T, ph * 6, nxtW, w, lane);
      const short8 a = ldsA(Xn, 192, mt << 4, kk << 5, lane);
      const u16* curW = cur ? Wb1 : Wb0;
#pragma unroll
      for (int p = 0; p < 6; ++p)
        acc1[p] = MFMA(a, ldsB(curW, half * 6 + p, lane), acc1[p]);
      cur ^= 1;
    }
    // ---- GELU -> Hs ----
#pragma unroll
    for (int p = 0; p < 6; ++p) {
      const int lcol = ((half * 6 + p) << 4) + (lane & 15);
      const float bias = b1[ph * 192 + lcol];
#pragma unroll
      for (int i = 0; i < 4; ++i) {
        const int r = (mt << 4) + ((lane >> 4) << 2) + i;
        const float hv = acc1[p][i] + bias;
        const float ge = gelu_f(hv);
        const int cb = (lcol << 1) ^ ((r & 7) << 4);
        Hs[r * 192 + (cb >> 1)] = f2bf(ge);
      }
    }
    // ---- fc2 partial: K slice [ph*192, +192), acc2 persists ----
#pragma unroll
    for (int kk = 0; kk < 6; ++kk) {
      __syncthreads();  // Hs visible (first iter) + Wb[cur] ready
      u16* nxtW = cur ? Wb0 : Wb1;
      if (kk < 5)      stage768_w8(w2T, ph * 6 + kk + 1, nxtW, w, lane);
      else if (ph < 3) stage768_w8(w1T, (ph + 1) * 6, nxtW, w, lane);
      const short8 a = ldsA(Hs, 192, mt << 4, kk << 5, lane);
      const u16* curW = cur ? Wb1 : Wb0;
#pragma unroll
      for (int p = 0; p < 6; ++p)
        acc2[p] = MFMA(a, ldsB(curW, half * 6 + p, lane), acc2[p]);
      cur ^= 1;
    }
  }

  // ---- epilogue: fp32 acc2 (no bias) -> Ef, then ((out+acc2)+bias) RMW ----
  __syncthreads();  // all fc2 reads of Hs/Wb done
#pragma unroll
  for (int p = 0; p < 6; ++p) {
    const int col = ((half * 6 + p) << 4) + (lane & 15);
#pragma unroll
    for (int i = 0; i < 4; ++i) {
      const int r = (mt << 4) + ((lane >> 4) << 2) + i;
      Ef[r * 192 + (col ^ ((r & 7) << 2))] = acc2[p][i];
    }
  }
  __syncthreads();
  {
    const int tok = t >> 3;
    const int ch0 = (t & 7) * 24;
    float* op = out + (T0 + tok) * 192 + ch0;
    const float* erow = Ef + tok * 192;
    const int swz = (tok & 7) << 2;
#pragma unroll
    for (int q = 0; q < 6; ++q) {
      const float4 ov = *(const float4*)(erow + ((ch0 + q * 4) ^ swz));
      const float4 bv = *(const float4*)(bo + ch0 + q * 4);
      float4 xv = *(const float4*)(op + q * 4);
      xv.x = (xv.x + ov.x) + bv.x;
      xv.y = (xv.y + ov.y) + bv.y;
      xv.z = (xv.z + ov.z) + bv.z;
      xv.w = (xv.w + ov.w) + bv.w;
      *(float4*)(op + q * 4) = xv;
    }
  }
}

// ---------------------------------------------------------------------------
extern "C" void kernel_launch(void* const* d_in, const int* in_sizes, int n_in,
                              void* d_out, int out_size, void* d_ws, size_t ws_size,
                              hipStream_t stream) {
  const float* x    = (const float*)d_in[0];
  const float* n1g  = (const float*)d_in[1];
  const float* n1b  = (const float*)d_in[2];
  const float* qkvw = (const float*)d_in[3];
  const float* qkvb = (const float*)d_in[4];
  const float* rpb  = (const float*)d_in[5];
  const float* pw   = (const float*)d_in[6];
  const float* pb   = (const float*)d_in[7];
  const float* n2g  = (const float*)d_in[8];
  const float* n2b  = (const float*)d_in[9];
  const float* w1   = (const float*)d_in[10];
  const float* b1   = (const float*)d_in[11];
  const float* w2   = (const float*)d_in[12];
  const float* b2   = (const float*)d_in[13];
  float* out = (float*)d_out;

  u16* hw    = (u16*)d_ws;                       // 131072*192 bf16 = 50.3 MB
  u16* wqkvT = hw + (size_t)131072 * 192;        // chunk-ordered [6][4][576][8]
  u16* projT = wqkvT + 576 * 192;                // chunk-ordered [6][4][192][8]
  u16* w1T   = projT + 192 * 192;                // chunk-ordered [4][6][4][192][8]
  u16* w2T   = w1T + 768 * 192;                  // chunk-ordered [4][6][4][192][8]
  float* biasTab = (float*)(w2T + (size_t)192 * 768);  // [4][6][64][64] fp32

  prep_kernel<<<576, 256, 0, stream>>>(qkvw, pw, w1, w2, rpb,
                                       wqkvT, projT, w1T, w2T, biasTab);
  attn_kernel<<<2048, 512, 0, stream>>>(x, n1g, n1b, wqkvT, qkvb, biasTab, hw);
  proj_kernel<<<2048, 256, 0, stream>>>(hw, projT, pb, x, out);
  mlp_kernel<<<2048, 512, 0, stream>>>(out, n2g, n2b, w1T, b1, w2T, b2);
}